// Round 1
// baseline (6650.620 us; speedup 1.0000x reference)
//
#include <hip/hip_runtime.h>
#include <hip/hip_bf16.h>
#include <stdint.h>

#define NODES 50000
#define EDGES 800000
#define DIM 256
#define NREL 8

typedef unsigned short u16;
typedef __attribute__((ext_vector_type(8))) __bf16 bf16x8;
typedef __attribute__((ext_vector_type(4))) float f32x4;

#define GLOBAL_AS __attribute__((address_space(1)))
#define LDS_AS __attribute__((address_space(3)))

__device__ __forceinline__ u16 f2bf(float f) {
  uint32_t u = __builtin_bit_cast(uint32_t, f);
  u += 0x7FFFu + ((u >> 16) & 1u);   // RNE; inputs are finite
  return (u16)(u >> 16);
}

// out[n][o] = bias[o] for all n (12.8M f32 = 3.2M float4)
__global__ void k_init_out(float* __restrict__ out, const float* __restrict__ bias) {
  int i = blockIdx.x * blockDim.x + threadIdx.x;
  ((float4*)out)[i] = ((const float4*)bias)[i & 63];
}

__global__ void k_cvt(const float* __restrict__ in, u16* __restrict__ outp, int n4) {
  int i = blockIdx.x * blockDim.x + threadIdx.x;
  if (i >= n4) return;
  float4 v = ((const float4*)in)[i];
  ushort4 o;
  o.x = f2bf(v.x); o.y = f2bf(v.y); o.z = f2bf(v.z); o.w = f2bf(v.w);
  ((ushort4*)outp)[i] = o;
}

// meta layout (ints): [0..7] counts, [8..16] offsets (9), [17..24] cursors
__global__ void k_zero8(int* __restrict__ meta) {
  if (threadIdx.x < 8) meta[threadIdx.x] = 0;
}

__global__ void k_hist(const int* __restrict__ et, int* __restrict__ meta) {
  int e = blockIdx.x * blockDim.x + threadIdx.x;
  if (e < EDGES) atomicAdd(&meta[et[e]], 1);
}

__global__ void k_scan(int* __restrict__ meta) {
  if (threadIdx.x == 0) {
    int s = 0;
    for (int r = 0; r < NREL; ++r) { meta[8 + r] = s; meta[17 + r] = s; s += meta[r]; }
    meta[16] = s;
  }
}

__global__ void k_scatter(const int* __restrict__ et, int* __restrict__ meta,
                          int* __restrict__ perm) {
  int e = blockIdx.x * blockDim.x + threadIdx.x;
  if (e < EDGES) {
    int p = atomicAdd(&meta[17 + et[e]], 1);  // order within bin irrelevant (sum commutes)
    perm[p] = e;
  }
}

// Per-relation gathered GEMM: msgs[e][o] = sum_i xb[src_e][i] * W[r][o][i], atomically
// scattered to out[dst_e]. Tile: BM=128 edges x BN=128 out-cols, BK=32, 4 waves (2x2 of 64x64).
// LDS tiles [row][32k] (64B rows) with chunk XOR-swizzle swz(l)=(l&3)^((l>>2)&3)^(l>>4):
// identical lane-constant on the global_load_lds source side and the ds_read_b128 side.
__global__ __launch_bounds__(256) void k_gemm(
    const u16* __restrict__ xb, const u16* __restrict__ wb,
    const int* __restrict__ perm, const int* __restrict__ meta,
    const int* __restrict__ esrc, const int* __restrict__ edst,
    float* __restrict__ out)
{
  const int r = blockIdx.z;
  const int estart = meta[8 + r];
  const int eend   = meta[9 + r];
  const int base = estart + (int)blockIdx.x * 128;
  if (base >= eend) return;
  const int mcount = min(128, eend - base);
  const int ny = blockIdx.y;  // 0/1 -> output cols [ny*128, ny*128+128)

  __shared__ int s_src[128];
  __shared__ int s_dst[128];
  __shared__ __align__(16) u16 s_a[128 * 32];  // 8KB
  __shared__ __align__(16) u16 s_b[128 * 32];  // 8KB

  const int tid = threadIdx.x;
  if (tid < 128) {
    int sv = 0, dv = 0;
    if (tid < mcount) { int e = perm[base + tid]; sv = esrc[e]; dv = edst[e]; }
    s_src[tid] = sv; s_dst[tid] = dv;
  }
  __syncthreads();

  const int lane = tid & 63;
  const int wv = tid >> 6;
  const int wr = wv >> 1, wc = wv & 1;
  const int swz = (lane & 3) ^ ((lane >> 2) & 3) ^ (lane >> 4);  // 16B-chunk index

  f32x4 acc[4][4];
#pragma unroll
  for (int m = 0; m < 4; ++m)
#pragma unroll
    for (int n = 0; n < 4; ++n) acc[m][n] = f32x4{0.f, 0.f, 0.f, 0.f};

  const int arow0 = wv * 32;  // this wave stages rows [arow0, arow0+32)
  const size_t wbase = ((size_t)r << 16) + ((size_t)ny << 15);  // u16 units

  for (int ks = 0; ks < 8; ++ks) {
#pragma unroll
    for (int c2 = 0; c2 < 2; ++c2) {
      const int rowb = arow0 + c2 * 16;        // 16 rows x 64B = 1KB per call
      const int row  = rowb + (lane >> 2);
      // A: gather edge src rows of xb (per-lane global addr; linear LDS dest)
      const u16* ga = xb + ((size_t)s_src[row] << 8) + (ks << 5) + (swz << 3);
      __builtin_amdgcn_global_load_lds((const GLOBAL_AS uint32_t*)ga,
                                       (LDS_AS uint32_t*)(s_a + rowb * 32), 16, 0, 0);
      // B: W[r][o][i] rows (o = ny*128 + row), contiguous in i
      const u16* gb = wb + wbase + ((size_t)row << 8) + (ks << 5) + (swz << 3);
      __builtin_amdgcn_global_load_lds((const GLOBAL_AS uint32_t*)gb,
                                       (LDS_AS uint32_t*)(s_b + rowb * 32), 16, 0, 0);
    }
    __syncthreads();  // drains vmcnt before barrier (compiler-inserted)

    bf16x8 af[4], bfr[4];
#pragma unroll
    for (int m = 0; m < 4; ++m)
      af[m] = *(const bf16x8*)(s_a + (wr * 64 + m * 16 + (lane & 15)) * 32 + swz * 8);
#pragma unroll
    for (int n = 0; n < 4; ++n)
      bfr[n] = *(const bf16x8*)(s_b + (wc * 64 + n * 16 + (lane & 15)) * 32 + swz * 8);
#pragma unroll
    for (int m = 0; m < 4; ++m)
#pragma unroll
      for (int n = 0; n < 4; ++n)
        acc[m][n] = __builtin_amdgcn_mfma_f32_16x16x32_bf16(af[m], bfr[n], acc[m][n], 0, 0, 0);
    __syncthreads();
  }

  // epilogue: atomic scatter. D layout: col=lane&15, row=(lane>>4)*4+reg (m89-verified)
  const int colb = ny * 128 + wc * 64 + (lane & 15);
#pragma unroll
  for (int m = 0; m < 4; ++m) {
#pragma unroll
    for (int q = 0; q < 4; ++q) {
      const int rl = wr * 64 + m * 16 + (lane >> 4) * 4 + q;
      if (rl < mcount) {
        float* op = out + (size_t)s_dst[rl] * DIM + colb;
#pragma unroll
        for (int n = 0; n < 4; ++n)
          atomicAdd(op + n * 16, acc[m][n][q]);
      }
    }
  }
}

// Correctness-only fallback if ws_size is too small for the staged pipeline.
__global__ void k_naive(const float* __restrict__ x, const float* __restrict__ w,
                        const int* __restrict__ esrc, const int* __restrict__ edst,
                        const int* __restrict__ et, float* __restrict__ out)
{
  const int lane = threadIdx.x & 63;
  int gw = (blockIdx.x * blockDim.x + threadIdx.x) >> 6;
  const int nw = (gridDim.x * blockDim.x) >> 6;
  for (int e = gw; e < EDGES; e += nw) {
    const int s = esrc[e], d = edst[e], r = et[e];
    const float* xr = x + (size_t)s * DIM;
    const float* wr0 = w + (size_t)r * DIM * DIM;
    float a[4] = {0.f, 0.f, 0.f, 0.f};
    for (int i = 0; i < DIM; ++i) {
      const float xv = xr[i];
#pragma unroll
      for (int c = 0; c < 4; ++c)
        a[c] += xv * wr0[(size_t)(lane + c * 64) * DIM + i];
    }
#pragma unroll
    for (int c = 0; c < 4; ++c)
      atomicAdd(&out[(size_t)d * DIM + lane + c * 64], a[c]);
  }
}

extern "C" void kernel_launch(void* const* d_in, const int* in_sizes, int n_in,
                              void* d_out, int out_size, void* d_ws, size_t ws_size,
                              hipStream_t stream) {
  const float* x    = (const float*)d_in[0];
  const float* w    = (const float*)d_in[1];
  const float* bias = (const float*)d_in[2];
  const int* eidx   = (const int*)d_in[3];
  const int* et     = (const int*)d_in[4];
  const int* esrc = eidx;
  const int* edst = eidx + EDGES;
  float* out = (float*)d_out;

  k_init_out<<<12500, 256, 0, stream>>>(out, bias);

  // ws layout
  size_t need = 0;
  auto pad = [](size_t v) { return (v + 255) & ~(size_t)255; };
  const size_t o_xb = need;   need = pad(need + (size_t)NODES * DIM * 2);
  const size_t o_wb = need;   need = pad(need + (size_t)NREL * DIM * DIM * 2);
  const size_t o_perm = need; need = pad(need + (size_t)EDGES * 4);
  const size_t o_meta = need; need = pad(need + 64 * 4);

  if (need <= ws_size) {
    char* ws = (char*)d_ws;
    u16* xb  = (u16*)(ws + o_xb);
    u16* wbb = (u16*)(ws + o_wb);
    int* perm = (int*)(ws + o_perm);
    int* meta = (int*)(ws + o_meta);

    k_cvt<<<12500, 256, 0, stream>>>(x, xb, NODES * DIM / 4);
    k_cvt<<<512, 256, 0, stream>>>(w, wbb, NREL * DIM * DIM / 4);
    k_zero8<<<1, 64, 0, stream>>>(meta);
    k_hist<<<3125, 256, 0, stream>>>(et, meta);
    k_scan<<<1, 1, 0, stream>>>(meta);
    k_scatter<<<3125, 256, 0, stream>>>(et, meta, perm);

    dim3 g(6250, 2, NREL);  // x: tile within bin (covers worst-case bin), y: n-tile, z: relation
    k_gemm<<<g, 256, 0, stream>>>(xb, wbb, perm, meta, esrc, edst, out);
  } else {
    k_naive<<<2048, 256, 0, stream>>>(x, w, esrc, edst, et, out);
  }
}

// Round 2
// 692.134 us; speedup vs baseline: 9.6089x; 9.6089x over previous
//
#include <hip/hip_runtime.h>
#include <hip/hip_bf16.h>
#include <stdint.h>

#define NODES 50000
#define EDGES 800000
#define DIM 256
#define NREL 8

typedef unsigned short u16;
typedef __attribute__((ext_vector_type(8))) __bf16 bf16x8;
typedef __attribute__((ext_vector_type(4))) float f32x4;

#define GLOBAL_AS __attribute__((address_space(1)))
#define LDS_AS __attribute__((address_space(3)))

__device__ __forceinline__ u16 f2bf(float f) {
  uint32_t u = __builtin_bit_cast(uint32_t, f);
  u += 0x7FFFu + ((u >> 16) & 1u);   // RNE; inputs are finite
  return (u16)(u >> 16);
}

// out[n][o] = bias[o] for all n (12.8M f32 = 3.2M float4)
__global__ void k_init_out(float* __restrict__ out, const float* __restrict__ bias) {
  int i = blockIdx.x * blockDim.x + threadIdx.x;
  ((float4*)out)[i] = ((const float4*)bias)[i & 63];
}

__global__ void k_cvt(const float* __restrict__ in, u16* __restrict__ outp, int n4) {
  int i = blockIdx.x * blockDim.x + threadIdx.x;
  if (i >= n4) return;
  float4 v = ((const float4*)in)[i];
  ushort4 o;
  o.x = f2bf(v.x); o.y = f2bf(v.y); o.z = f2bf(v.z); o.w = f2bf(v.w);
  ((ushort4*)outp)[i] = o;
}

// meta layout (ints): [0..7] counts, [8..16] offsets (9), [17..24] cursors
__global__ void k_zero8(int* __restrict__ meta) {
  if (threadIdx.x < 8) meta[threadIdx.x] = 0;
}

#define SORT_BLOCKS 256
#define SORT_CHUNK ((EDGES + SORT_BLOCKS - 1) / SORT_BLOCKS)

// Per-block LDS histogram, ONE global atomic per bin per block (G12: aggregate
// before atomics — round-1's 800K same-address atomics cost 2985us/kernel).
__global__ void k_hist(const int* __restrict__ et, int* __restrict__ meta) {
  __shared__ int lh[NREL];
  if (threadIdx.x < NREL) lh[threadIdx.x] = 0;
  __syncthreads();
  const int lo = blockIdx.x * SORT_CHUNK;
  const int hi = min(EDGES, lo + SORT_CHUNK);
  for (int e = lo + threadIdx.x; e < hi; e += blockDim.x)
    atomicAdd(&lh[et[e]], 1);
  __syncthreads();
  if (threadIdx.x < NREL && lh[threadIdx.x])
    atomicAdd(&meta[threadIdx.x], lh[threadIdx.x]);
}

__global__ void k_scan(int* __restrict__ meta) {
  if (threadIdx.x == 0) {
    int s = 0;
    for (int r = 0; r < NREL; ++r) { meta[8 + r] = s; meta[17 + r] = s; s += meta[r]; }
    meta[16] = s;
  }
}

// Two-pass per-block: count chunk -> reserve bin ranges (8 global atomics) ->
// scatter via LDS cursors. Order within a bin is irrelevant (sum commutes).
__global__ void k_scatter(const int* __restrict__ et, int* __restrict__ meta,
                          int* __restrict__ perm) {
  __shared__ int lh[NREL];  // count, then unused
  __shared__ int lc[NREL];  // global write cursor per bin
  if (threadIdx.x < NREL) lh[threadIdx.x] = 0;
  __syncthreads();
  const int lo = blockIdx.x * SORT_CHUNK;
  const int hi = min(EDGES, lo + SORT_CHUNK);
  for (int e = lo + threadIdx.x; e < hi; e += blockDim.x)
    atomicAdd(&lh[et[e]], 1);
  __syncthreads();
  if (threadIdx.x < NREL) {
    const int c = lh[threadIdx.x];
    lc[threadIdx.x] = c ? atomicAdd(&meta[17 + threadIdx.x], c) : 0;
  }
  __syncthreads();
  for (int e = lo + threadIdx.x; e < hi; e += blockDim.x) {
    const int p = atomicAdd(&lc[et[e]], 1);  // LDS atomic -> global slot
    perm[p] = e;
  }
}

// Per-relation gathered GEMM: msgs[e][o] = sum_i xb[src_e][i] * W[r][o][i], atomically
// scattered to out[dst_e]. Tile: BM=128 edges x BN=128 out-cols, BK=32, 4 waves (2x2 of 64x64).
// LDS tiles [row][32k] (64B rows) with chunk XOR-swizzle swz(l)=(l&3)^((l>>2)&3)^(l>>4):
// identical lane-constant on the global_load_lds source side and the ds_read_b128 side.
__global__ __launch_bounds__(256) void k_gemm(
    const u16* __restrict__ xb, const u16* __restrict__ wb,
    const int* __restrict__ perm, const int* __restrict__ meta,
    const int* __restrict__ esrc, const int* __restrict__ edst,
    float* __restrict__ out)
{
  const int r = blockIdx.z;
  const int estart = meta[8 + r];
  const int eend   = meta[9 + r];
  const int base = estart + (int)blockIdx.x * 128;
  if (base >= eend) return;
  const int mcount = min(128, eend - base);
  const int ny = blockIdx.y;  // 0/1 -> output cols [ny*128, ny*128+128)

  __shared__ int s_src[128];
  __shared__ int s_dst[128];
  __shared__ __align__(16) u16 s_a[128 * 32];  // 8KB
  __shared__ __align__(16) u16 s_b[128 * 32];  // 8KB

  const int tid = threadIdx.x;
  if (tid < 128) {
    int sv = 0, dv = 0;
    if (tid < mcount) { int e = perm[base + tid]; sv = esrc[e]; dv = edst[e]; }
    s_src[tid] = sv; s_dst[tid] = dv;
  }
  __syncthreads();

  const int lane = tid & 63;
  const int wv = tid >> 6;
  const int wr = wv >> 1, wc = wv & 1;
  const int swz = (lane & 3) ^ ((lane >> 2) & 3) ^ (lane >> 4);  // 16B-chunk index

  f32x4 acc[4][4];
#pragma unroll
  for (int m = 0; m < 4; ++m)
#pragma unroll
    for (int n = 0; n < 4; ++n) acc[m][n] = f32x4{0.f, 0.f, 0.f, 0.f};

  const int arow0 = wv * 32;  // this wave stages rows [arow0, arow0+32)
  const size_t wbase = ((size_t)r << 16) + ((size_t)ny << 15);  // u16 units

  for (int ks = 0; ks < 8; ++ks) {
#pragma unroll
    for (int c2 = 0; c2 < 2; ++c2) {
      const int rowb = arow0 + c2 * 16;        // 16 rows x 64B = 1KB per call
      const int row  = rowb + (lane >> 2);
      // A: gather edge src rows of xb (per-lane global addr; linear LDS dest)
      const u16* ga = xb + ((size_t)s_src[row] << 8) + (ks << 5) + (swz << 3);
      __builtin_amdgcn_global_load_lds((const GLOBAL_AS uint32_t*)ga,
                                       (LDS_AS uint32_t*)(s_a + rowb * 32), 16, 0, 0);
      // B: W[r][o][i] rows (o = ny*128 + row), contiguous in i
      const u16* gb = wb + wbase + ((size_t)row << 8) + (ks << 5) + (swz << 3);
      __builtin_amdgcn_global_load_lds((const GLOBAL_AS uint32_t*)gb,
                                       (LDS_AS uint32_t*)(s_b + rowb * 32), 16, 0, 0);
    }
    __syncthreads();  // drains vmcnt before barrier (compiler-inserted)

    bf16x8 af[4], bfr[4];
#pragma unroll
    for (int m = 0; m < 4; ++m)
      af[m] = *(const bf16x8*)(s_a + (wr * 64 + m * 16 + (lane & 15)) * 32 + swz * 8);
#pragma unroll
    for (int n = 0; n < 4; ++n)
      bfr[n] = *(const bf16x8*)(s_b + (wc * 64 + n * 16 + (lane & 15)) * 32 + swz * 8);
#pragma unroll
    for (int m = 0; m < 4; ++m)
#pragma unroll
      for (int n = 0; n < 4; ++n)
        acc[m][n] = __builtin_amdgcn_mfma_f32_16x16x32_bf16(af[m], bfr[n], acc[m][n], 0, 0, 0);
    __syncthreads();
  }

  // epilogue: atomic scatter. D layout: col=lane&15, row=(lane>>4)*4+reg (m89-verified)
  const int colb = ny * 128 + wc * 64 + (lane & 15);
#pragma unroll
  for (int m = 0; m < 4; ++m) {
#pragma unroll
    for (int q = 0; q < 4; ++q) {
      const int rl = wr * 64 + m * 16 + (lane >> 4) * 4 + q;
      if (rl < mcount) {
        float* op = out + (size_t)s_dst[rl] * DIM + colb;
#pragma unroll
        for (int n = 0; n < 4; ++n)
          atomicAdd(op + n * 16, acc[m][n][q]);
      }
    }
  }
}

// Correctness-only fallback if ws_size is too small for the staged pipeline.
__global__ void k_naive(const float* __restrict__ x, const float* __restrict__ w,
                        const int* __restrict__ esrc, const int* __restrict__ edst,
                        const int* __restrict__ et, float* __restrict__ out)
{
  const int lane = threadIdx.x & 63;
  int gw = (blockIdx.x * blockDim.x + threadIdx.x) >> 6;
  const int nw = (gridDim.x * blockDim.x) >> 6;
  for (int e = gw; e < EDGES; e += nw) {
    const int s = esrc[e], d = edst[e], r = et[e];
    const float* xr = x + (size_t)s * DIM;
    const float* wr0 = w + (size_t)r * DIM * DIM;
    float a[4] = {0.f, 0.f, 0.f, 0.f};
    for (int i = 0; i < DIM; ++i) {
      const float xv = xr[i];
#pragma unroll
      for (int c = 0; c < 4; ++c)
        a[c] += xv * wr0[(size_t)(lane + c * 64) * DIM + i];
    }
#pragma unroll
    for (int c = 0; c < 4; ++c)
      atomicAdd(&out[(size_t)d * DIM + lane + c * 64], a[c]);
  }
}

extern "C" void kernel_launch(void* const* d_in, const int* in_sizes, int n_in,
                              void* d_out, int out_size, void* d_ws, size_t ws_size,
                              hipStream_t stream) {
  const float* x    = (const float*)d_in[0];
  const float* w    = (const float*)d_in[1];
  const float* bias = (const float*)d_in[2];
  const int* eidx   = (const int*)d_in[3];
  const int* et     = (const int*)d_in[4];
  const int* esrc = eidx;
  const int* edst = eidx + EDGES;
  float* out = (float*)d_out;

  k_init_out<<<12500, 256, 0, stream>>>(out, bias);

  // ws layout
  size_t need = 0;
  auto pad = [](size_t v) { return (v + 255) & ~(size_t)255; };
  const size_t o_xb = need;   need = pad(need + (size_t)NODES * DIM * 2);
  const size_t o_wb = need;   need = pad(need + (size_t)NREL * DIM * DIM * 2);
  const size_t o_perm = need; need = pad(need + (size_t)EDGES * 4);
  const size_t o_meta = need; need = pad(need + 64 * 4);

  if (need <= ws_size) {
    char* ws = (char*)d_ws;
    u16* xb  = (u16*)(ws + o_xb);
    u16* wbb = (u16*)(ws + o_wb);
    int* perm = (int*)(ws + o_perm);
    int* meta = (int*)(ws + o_meta);

    k_cvt<<<12500, 256, 0, stream>>>(x, xb, NODES * DIM / 4);
    k_cvt<<<512, 256, 0, stream>>>(w, wbb, NREL * DIM * DIM / 4);
    k_zero8<<<1, 64, 0, stream>>>(meta);
    k_hist<<<SORT_BLOCKS, 256, 0, stream>>>(et, meta);
    k_scan<<<1, 1, 0, stream>>>(meta);
    k_scatter<<<SORT_BLOCKS, 256, 0, stream>>>(et, meta, perm);

    dim3 g(6250, 2, NREL);  // x: tile within bin (covers worst-case bin), y: n-tile, z: relation
    k_gemm<<<g, 256, 0, stream>>>(xb, wbb, perm, meta, esrc, edst, out);
  } else {
    k_naive<<<2048, 256, 0, stream>>>(x, w, esrc, edst, et, out);
  }
}

// Round 3
// 289.746 us; speedup vs baseline: 22.9532x; 2.3888x over previous
//
#include <hip/hip_runtime.h>
#include <hip/hip_bf16.h>
#include <stdint.h>

#define NODES 50000
#define EDGES 800000
#define DIM 256
#define NREL 8
#define NJ (NREL * DIM)  // 2048 combined output cols (r*256+o)

typedef unsigned short u16;
typedef __attribute__((ext_vector_type(8))) __bf16 bf16x8;
typedef __attribute__((ext_vector_type(4))) float f32x4;

#define GLOBAL_AS __attribute__((address_space(1)))
#define LDS_AS __attribute__((address_space(3)))

__device__ __forceinline__ u16 f2bf(float f) {
  uint32_t u = __builtin_bit_cast(uint32_t, f);
  u += 0x7FFFu + ((u >> 16) & 1u);  // RNE; inputs finite
  return (u16)(u >> 16);
}
__device__ __forceinline__ float bf2f(u16 u) {
  uint32_t t = (uint32_t)u << 16;
  return __builtin_bit_cast(float, t);
}

__global__ void k_cvt(const float* __restrict__ in, u16* __restrict__ outp, int n4) {
  int i = blockIdx.x * blockDim.x + threadIdx.x;
  if (i >= n4) return;
  float4 v = ((const float4*)in)[i];
  ushort4 o;
  o.x = f2bf(v.x); o.y = f2bf(v.y); o.z = f2bf(v.z); o.w = f2bf(v.w);
  ((ushort4*)outp)[i] = o;
}

// ---------------- Tier A: dense GEMM -> dst-sorted gather-reduce ----------------

// h[n][j] = sum_i xb[n][i] * wb[j][i], j = r*256+o (Wflat rows ARE (r,o) pairs).
// BM=128 x BN=128, BK=32, 4 waves (2x2 of 64x64), m97-style global_load_lds staging,
// chunk XOR-swizzle identical on source and ds_read sides (G21 both-sides rule).
__global__ __launch_bounds__(256) void k_gemm(
    const u16* __restrict__ xb, const u16* __restrict__ wb, u16* __restrict__ h)
{
  const int mbase = blockIdx.x * 128;
  const int jbase = blockIdx.y * 128;

  __shared__ __align__(16) u16 s_a[128 * 32];  // 8KB
  __shared__ __align__(16) u16 s_b[128 * 32];  // 8KB

  const int tid = threadIdx.x;
  const int lane = tid & 63;
  const int wv = tid >> 6;
  const int wr = wv >> 1, wc = wv & 1;
  const int swz = (lane & 3) ^ ((lane >> 2) & 3) ^ (lane >> 4);  // 16B-chunk idx

  f32x4 acc[4][4];
#pragma unroll
  for (int m = 0; m < 4; ++m)
#pragma unroll
    for (int n = 0; n < 4; ++n) acc[m][n] = f32x4{0.f, 0.f, 0.f, 0.f};

  const int arow0 = wv * 32;  // this wave stages rows [arow0, arow0+32)

  for (int ks = 0; ks < 8; ++ks) {
#pragma unroll
    for (int c2 = 0; c2 < 2; ++c2) {
      const int rowb = arow0 + c2 * 16;
      const int row  = rowb + (lane >> 2);
      const int ar = min(mbase + row, NODES - 1);  // clamp last tile
      const u16* ga = xb + ((size_t)ar << 8) + (ks << 5) + (swz << 3);
      __builtin_amdgcn_global_load_lds((const GLOBAL_AS uint32_t*)ga,
                                       (LDS_AS uint32_t*)(s_a + rowb * 32), 16, 0, 0);
      const u16* gb = wb + ((size_t)(jbase + row) << 8) + (ks << 5) + (swz << 3);
      __builtin_amdgcn_global_load_lds((const GLOBAL_AS uint32_t*)gb,
                                       (LDS_AS uint32_t*)(s_b + rowb * 32), 16, 0, 0);
    }
    __syncthreads();

    bf16x8 af[4], bfr[4];
#pragma unroll
    for (int m = 0; m < 4; ++m)
      af[m] = *(const bf16x8*)(s_a + (wr * 64 + m * 16 + (lane & 15)) * 32 + swz * 8);
#pragma unroll
    for (int n = 0; n < 4; ++n)
      bfr[n] = *(const bf16x8*)(s_b + (wc * 64 + n * 16 + (lane & 15)) * 32 + swz * 8);
#pragma unroll
    for (int m = 0; m < 4; ++m)
#pragma unroll
      for (int n = 0; n < 4; ++n)
        acc[m][n] = __builtin_amdgcn_mfma_f32_16x16x32_bf16(af[m], bfr[n], acc[m][n], 0, 0, 0);
    __syncthreads();
  }

  // store bf16 h. D layout: col=lane&15, row=(lane>>4)*4+q (m89-verified)
  const int colb = jbase + wc * 64 + (lane & 15);
#pragma unroll
  for (int m = 0; m < 4; ++m) {
#pragma unroll
    for (int q = 0; q < 4; ++q) {
      const int grow = mbase + wr * 64 + m * 16 + (lane >> 4) * 4 + q;
      if (grow < NODES) {
        u16* hp = h + (size_t)grow * NJ + colb;
#pragma unroll
        for (int n = 0; n < 4; ++n) hp[n * 16] = f2bf(acc[m][n][q]);
      }
    }
  }
}

// ---- counting sort by dst (50K bins; ~16-way contention is harmless) ----
#define SCAN_BLOCKS 196  // ceil(50000/256)

__global__ void k_zero_n(int* __restrict__ cnt) {
  int i = blockIdx.x * blockDim.x + threadIdx.x;
  if (i < NODES) cnt[i] = 0;
}
__global__ void k_hist2(const int* __restrict__ edst, int* __restrict__ cnt) {
  int e = blockIdx.x * blockDim.x + threadIdx.x;
  if (e < EDGES) atomicAdd(&cnt[edst[e]], 1);
}
__global__ void k_bsum(const int* __restrict__ cnt, int* __restrict__ bs) {
  int i = blockIdx.x * blockDim.x + threadIdx.x;
  int v = (i < NODES) ? cnt[i] : 0;
#pragma unroll
  for (int o = 32; o; o >>= 1) v += __shfl_down(v, o);
  __shared__ int wsum[4];
  if ((threadIdx.x & 63) == 0) wsum[threadIdx.x >> 6] = v;
  __syncthreads();
  if (threadIdx.x == 0) bs[blockIdx.x] = wsum[0] + wsum[1] + wsum[2] + wsum[3];
}
__global__ void k_bscan(int* __restrict__ bs) {  // exclusive scan of SCAN_BLOCKS, 1 block
  __shared__ int tmp[SCAN_BLOCKS];
  int t = threadIdx.x;
  if (t < SCAN_BLOCKS) tmp[t] = bs[t];
  __syncthreads();
  if (t == 0) {
    int s = 0;
    for (int i = 0; i < SCAN_BLOCKS; ++i) { int c = tmp[i]; tmp[i] = s; s += c; }
  }
  __syncthreads();
  if (t < SCAN_BLOCKS) bs[t] = tmp[t];
}
__global__ void k_scan2(const int* __restrict__ cnt, const int* __restrict__ bs,
                        int* __restrict__ row_ptr, int* __restrict__ cur) {
  int t = threadIdx.x;
  int i = blockIdx.x * blockDim.x + t;
  int v = (i < NODES) ? cnt[i] : 0;
  __shared__ int tmp[256];
  tmp[t] = v;
  __syncthreads();
  for (int o = 1; o < 256; o <<= 1) {  // Hillis-Steele inclusive
    int u = (t >= o) ? tmp[t - o] : 0;
    __syncthreads();
    tmp[t] += u;
    __syncthreads();
  }
  int val = bs[blockIdx.x] + tmp[t] - v;  // exclusive
  if (i <= NODES) row_ptr[i] = val;       // row_ptr[NODES] lands on EDGES
  if (i < NODES) cur[i] = val;
}
__global__ void k_scatter2(const int* __restrict__ esrc, const int* __restrict__ edst,
                           const int* __restrict__ et, int* __restrict__ cur,
                           int* __restrict__ sg) {
  int e = blockIdx.x * blockDim.x + threadIdx.x;
  if (e < EDGES) {
    int p = atomicAdd(&cur[edst[e]], 1);  // in-bin order irrelevant (sum commutes)
    sg[p] = esrc[e] * NREL + et[e];       // h row index: src*2048+et*256 = sg*256
  }
}

// One wave per dst node: gather ~deg(16) rows of h (512B each), f32-accumulate,
// +bias, single coalesced float4 row write. No atomics anywhere.
__global__ __launch_bounds__(256) void k_reduce(
    const u16* __restrict__ h, const int* __restrict__ row_ptr,
    const int* __restrict__ sg, const float* __restrict__ bias,
    float* __restrict__ out)
{
  const int wid = (int)((blockIdx.x * blockDim.x + threadIdx.x) >> 6);
  if (wid >= NODES) return;
  const int lane = threadIdx.x & 63;
  const int lo = row_ptr[wid], hi = row_ptr[wid + 1];
  const u16* hb = h + lane * 4;

  float a0 = 0.f, a1 = 0.f, a2 = 0.f, a3 = 0.f;
  int e = lo;
  for (; e + 4 <= hi; e += 4) {  // 4 independent gathers in flight
    const ushort4 v0 = *(const ushort4*)(hb + ((size_t)sg[e] << 8));
    const ushort4 v1 = *(const ushort4*)(hb + ((size_t)sg[e + 1] << 8));
    const ushort4 v2 = *(const ushort4*)(hb + ((size_t)sg[e + 2] << 8));
    const ushort4 v3 = *(const ushort4*)(hb + ((size_t)sg[e + 3] << 8));
    a0 += (bf2f(v0.x) + bf2f(v1.x)) + (bf2f(v2.x) + bf2f(v3.x));
    a1 += (bf2f(v0.y) + bf2f(v1.y)) + (bf2f(v2.y) + bf2f(v3.y));
    a2 += (bf2f(v0.z) + bf2f(v1.z)) + (bf2f(v2.z) + bf2f(v3.z));
    a3 += (bf2f(v0.w) + bf2f(v1.w)) + (bf2f(v2.w) + bf2f(v3.w));
  }
  for (; e < hi; ++e) {
    const ushort4 v = *(const ushort4*)(hb + ((size_t)sg[e] << 8));
    a0 += bf2f(v.x); a1 += bf2f(v.y); a2 += bf2f(v.z); a3 += bf2f(v.w);
  }
  const float4 b = ((const float4*)bias)[lane];
  float4 o;
  o.x = a0 + b.x; o.y = a1 + b.y; o.z = a2 + b.z; o.w = a3 + b.w;
  ((float4*)out)[(size_t)wid * 64 + lane] = o;
}

// ---------------- Tier B: round-2 path (per-relation gathered GEMM + atomics) ----------------

__global__ void k_init_out(float* __restrict__ out, const float* __restrict__ bias) {
  int i = blockIdx.x * blockDim.x + threadIdx.x;
  ((float4*)out)[i] = ((const float4*)bias)[i & 63];
}
__global__ void k_zero8(int* __restrict__ meta) {
  if (threadIdx.x < 8) meta[threadIdx.x] = 0;
}
#define SORT_BLOCKS 256
#define SORT_CHUNK ((EDGES + SORT_BLOCKS - 1) / SORT_BLOCKS)
__global__ void k_hist(const int* __restrict__ et, int* __restrict__ meta) {
  __shared__ int lh[NREL];
  if (threadIdx.x < NREL) lh[threadIdx.x] = 0;
  __syncthreads();
  const int lo = blockIdx.x * SORT_CHUNK, hi = min(EDGES, lo + SORT_CHUNK);
  for (int e = lo + threadIdx.x; e < hi; e += blockDim.x) atomicAdd(&lh[et[e]], 1);
  __syncthreads();
  if (threadIdx.x < NREL && lh[threadIdx.x]) atomicAdd(&meta[threadIdx.x], lh[threadIdx.x]);
}
__global__ void k_scan(int* __restrict__ meta) {
  if (threadIdx.x == 0) {
    int s = 0;
    for (int r = 0; r < NREL; ++r) { meta[8 + r] = s; meta[17 + r] = s; s += meta[r]; }
    meta[16] = s;
  }
}
__global__ void k_scatter(const int* __restrict__ et, int* __restrict__ meta,
                          int* __restrict__ perm) {
  __shared__ int lh[NREL];
  __shared__ int lc[NREL];
  if (threadIdx.x < NREL) lh[threadIdx.x] = 0;
  __syncthreads();
  const int lo = blockIdx.x * SORT_CHUNK, hi = min(EDGES, lo + SORT_CHUNK);
  for (int e = lo + threadIdx.x; e < hi; e += blockDim.x) atomicAdd(&lh[et[e]], 1);
  __syncthreads();
  if (threadIdx.x < NREL) {
    const int c = lh[threadIdx.x];
    lc[threadIdx.x] = c ? atomicAdd(&meta[17 + threadIdx.x], c) : 0;
  }
  __syncthreads();
  for (int e = lo + threadIdx.x; e < hi; e += blockDim.x) {
    const int p = atomicAdd(&lc[et[e]], 1);
    perm[p] = e;
  }
}
__global__ __launch_bounds__(256) void k_gemm_b(
    const u16* __restrict__ xb, const u16* __restrict__ wb,
    const int* __restrict__ perm, const int* __restrict__ meta,
    const int* __restrict__ esrc, const int* __restrict__ edst,
    float* __restrict__ out)
{
  const int r = blockIdx.z;
  const int estart = meta[8 + r], eend = meta[9 + r];
  const int base = estart + (int)blockIdx.x * 128;
  if (base >= eend) return;
  const int mcount = min(128, eend - base);
  const int ny = blockIdx.y;
  __shared__ int s_src[128];
  __shared__ int s_dst[128];
  __shared__ __align__(16) u16 s_a[128 * 32];
  __shared__ __align__(16) u16 s_b[128 * 32];
  const int tid = threadIdx.x;
  if (tid < 128) {
    int sv = 0, dv = 0;
    if (tid < mcount) { int e = perm[base + tid]; sv = esrc[e]; dv = edst[e]; }
    s_src[tid] = sv; s_dst[tid] = dv;
  }
  __syncthreads();
  const int lane = tid & 63;
  const int wv = tid >> 6;
  const int wr = wv >> 1, wc = wv & 1;
  const int swz = (lane & 3) ^ ((lane >> 2) & 3) ^ (lane >> 4);
  f32x4 acc[4][4];
#pragma unroll
  for (int m = 0; m < 4; ++m)
#pragma unroll
    for (int n = 0; n < 4; ++n) acc[m][n] = f32x4{0.f, 0.f, 0.f, 0.f};
  const int arow0 = wv * 32;
  const size_t wbase = ((size_t)r << 16) + ((size_t)ny << 15);
  for (int ks = 0; ks < 8; ++ks) {
#pragma unroll
    for (int c2 = 0; c2 < 2; ++c2) {
      const int rowb = arow0 + c2 * 16;
      const int row  = rowb + (lane >> 2);
      const u16* ga = xb + ((size_t)s_src[row] << 8) + (ks << 5) + (swz << 3);
      __builtin_amdgcn_global_load_lds((const GLOBAL_AS uint32_t*)ga,
                                       (LDS_AS uint32_t*)(s_a + rowb * 32), 16, 0, 0);
      const u16* gb = wb + wbase + ((size_t)row << 8) + (ks << 5) + (swz << 3);
      __builtin_amdgcn_global_load_lds((const GLOBAL_AS uint32_t*)gb,
                                       (LDS_AS uint32_t*)(s_b + rowb * 32), 16, 0, 0);
    }
    __syncthreads();
    bf16x8 af[4], bfr[4];
#pragma unroll
    for (int m = 0; m < 4; ++m)
      af[m] = *(const bf16x8*)(s_a + (wr * 64 + m * 16 + (lane & 15)) * 32 + swz * 8);
#pragma unroll
    for (int n = 0; n < 4; ++n)
      bfr[n] = *(const bf16x8*)(s_b + (wc * 64 + n * 16 + (lane & 15)) * 32 + swz * 8);
#pragma unroll
    for (int m = 0; m < 4; ++m)
#pragma unroll
      for (int n = 0; n < 4; ++n)
        acc[m][n] = __builtin_amdgcn_mfma_f32_16x16x32_bf16(af[m], bfr[n], acc[m][n], 0, 0, 0);
    __syncthreads();
  }
  const int colb = ny * 128 + wc * 64 + (lane & 15);
#pragma unroll
  for (int m = 0; m < 4; ++m) {
#pragma unroll
    for (int q = 0; q < 4; ++q) {
      const int rl = wr * 64 + m * 16 + (lane >> 4) * 4 + q;
      if (rl < mcount) {
        float* op = out + (size_t)s_dst[rl] * DIM + colb;
#pragma unroll
        for (int n = 0; n < 4; ++n) atomicAdd(op + n * 16, acc[m][n][q]);
      }
    }
  }
}

// Tier C: correctness-only fallback.
__global__ void k_naive(const float* __restrict__ x, const float* __restrict__ w,
                        const int* __restrict__ esrc, const int* __restrict__ edst,
                        const int* __restrict__ et, float* __restrict__ out)
{
  const int lane = threadIdx.x & 63;
  int gw = (blockIdx.x * blockDim.x + threadIdx.x) >> 6;
  const int nw = (gridDim.x * blockDim.x) >> 6;
  for (int e = gw; e < EDGES; e += nw) {
    const int s = esrc[e], d = edst[e], r = et[e];
    const float* xr = x + (size_t)s * DIM;
    const float* wr0 = w + (size_t)r * DIM * DIM;
    float a[4] = {0.f, 0.f, 0.f, 0.f};
    for (int i = 0; i < DIM; ++i) {
      const float xv = xr[i];
#pragma unroll
      for (int c = 0; c < 4; ++c) a[c] += xv * wr0[(size_t)(lane + c * 64) * DIM + i];
    }
#pragma unroll
    for (int c = 0; c < 4; ++c) atomicAdd(&out[(size_t)d * DIM + lane + c * 64], a[c]);
  }
}

extern "C" void kernel_launch(void* const* d_in, const int* in_sizes, int n_in,
                              void* d_out, int out_size, void* d_ws, size_t ws_size,
                              hipStream_t stream) {
  const float* x    = (const float*)d_in[0];
  const float* w    = (const float*)d_in[1];
  const float* bias = (const float*)d_in[2];
  const int* eidx   = (const int*)d_in[3];
  const int* et     = (const int*)d_in[4];
  const int* esrc = eidx;
  const int* edst = eidx + EDGES;
  float* out = (float*)d_out;

  auto pad = [](size_t v) { return (v + 255) & ~(size_t)255; };

  // Tier A layout
  size_t needA = 0;
  const size_t a_xb = needA;  needA = pad(needA + (size_t)NODES * DIM * 2);
  const size_t a_wb = needA;  needA = pad(needA + (size_t)NREL * DIM * DIM * 2);
  const size_t a_h  = needA;  needA = pad(needA + (size_t)NODES * NJ * 2);
  const size_t a_cnt = needA; needA = pad(needA + (size_t)NODES * 4);
  const size_t a_rp  = needA; needA = pad(needA + ((size_t)NODES + 1) * 4);
  const size_t a_cur = needA; needA = pad(needA + (size_t)NODES * 4);
  const size_t a_bs  = needA; needA = pad(needA + (size_t)SCAN_BLOCKS * 4);
  const size_t a_sg  = needA; needA = pad(needA + (size_t)EDGES * 4);

  // Tier B layout
  size_t needB = 0;
  const size_t b_xb = needB;   needB = pad(needB + (size_t)NODES * DIM * 2);
  const size_t b_wb = needB;   needB = pad(needB + (size_t)NREL * DIM * DIM * 2);
  const size_t b_perm = needB; needB = pad(needB + (size_t)EDGES * 4);
  const size_t b_meta = needB; needB = pad(needB + 64 * 4);

  char* ws = (char*)d_ws;
  if (needA <= ws_size) {
    u16* xb = (u16*)(ws + a_xb);
    u16* wb = (u16*)(ws + a_wb);
    u16* h  = (u16*)(ws + a_h);
    int* cnt = (int*)(ws + a_cnt);
    int* rp  = (int*)(ws + a_rp);
    int* cur = (int*)(ws + a_cur);
    int* bs  = (int*)(ws + a_bs);
    int* sg  = (int*)(ws + a_sg);

    k_cvt<<<12500, 256, 0, stream>>>(x, xb, NODES * DIM / 4);
    k_cvt<<<512, 256, 0, stream>>>(w, wb, NREL * DIM * DIM / 4);
    k_zero_n<<<SCAN_BLOCKS, 256, 0, stream>>>(cnt);
    k_hist2<<<3125, 256, 0, stream>>>(edst, cnt);
    k_bsum<<<SCAN_BLOCKS, 256, 0, stream>>>(cnt, bs);
    k_bscan<<<1, 256, 0, stream>>>(bs);
    k_scan2<<<SCAN_BLOCKS, 256, 0, stream>>>(cnt, bs, rp, cur);
    k_scatter2<<<3125, 256, 0, stream>>>(esrc, edst, et, cur, sg);
    dim3 g((NODES + 127) / 128, NJ / 128);  // 391 x 16
    k_gemm<<<g, 256, 0, stream>>>(xb, wb, h);
    k_reduce<<<(NODES * 64 + 255) / 256, 256, 0, stream>>>(h, rp, sg, bias, out);
  } else if (needB <= ws_size) {
    u16* xb  = (u16*)(ws + b_xb);
    u16* wbb = (u16*)(ws + b_wb);
    int* perm = (int*)(ws + b_perm);
    int* meta = (int*)(ws + b_meta);
    k_init_out<<<12500, 256, 0, stream>>>(out, bias);
    k_cvt<<<12500, 256, 0, stream>>>(x, xb, NODES * DIM / 4);
    k_cvt<<<512, 256, 0, stream>>>(w, wbb, NREL * DIM * DIM / 4);
    k_zero8<<<1, 64, 0, stream>>>(meta);
    k_hist<<<SORT_BLOCKS, 256, 0, stream>>>(et, meta);
    k_scan<<<1, 1, 0, stream>>>(meta);
    k_scatter<<<SORT_BLOCKS, 256, 0, stream>>>(et, meta, perm);
    dim3 g(6250, 2, NREL);
    k_gemm_b<<<g, 256, 0, stream>>>(xb, wbb, perm, meta, esrc, edst, out);
  } else {
    k_init_out<<<12500, 256, 0, stream>>>(out, bias);
    k_naive<<<2048, 256, 0, stream>>>(x, w, esrc, edst, et, out);
  }
}